// Round 3
// baseline (4164.300 us; speedup 1.0000x reference)
//
#include <hip/hip_runtime.h>
#include <hip/hip_bf16.h>
#include <math.h>

#define EPSV 1e-8f

__device__ __forceinline__ float dsmall(float d){ return d > EPSV ? d : EPSV; }
__device__ __forceinline__ float sigf(float x){ return 1.f/(1.f+expf(-x)); }

// ---------------------------------------------------------------------------
// Transpose: W (R x C) -> WT (C x R)
// ---------------------------------------------------------------------------
__global__ __launch_bounds__(1024) void k_transpose(const float* __restrict__ W,
                                                    float* __restrict__ WT, int R, int C){
  __shared__ float t[32][33];
  int rb = blockIdx.y*32, cb = blockIdx.x*32;
  int r = rb + threadIdx.y, c = cb + threadIdx.x;
  if (r < R && c < C) t[threadIdx.y][threadIdx.x] = W[(size_t)r*C + c];
  __syncthreads();
  int rr = cb + threadIdx.y, cc = rb + threadIdx.x;
  if (rr < C && cc < R) WT[(size_t)rr*R + cc] = t[threadIdx.x][threadIdx.y];
}

// ---------------------------------------------------------------------------
// Generic z-batched tiled GEMM-like kernel. 64x64 tile, 256 thr, 4x4/thread.
// MODE 0: C=A(MxK)@B(NxK)^T + bias[n]
// MODE 1: C=(A*wscale^2)(MxK)@B(NxK)^T / dsmall(U[m]*V[n])
// MODE 2: C=A(MxK)@B(KxN) / dsmall(U[m])
// MODE 3: C=max_k A(MxK)*B(KxN)
// MODE 4: C=A(KxM)^T@B(KxN) / dsmall(U[m])
// MODE 5: C=max_k A(KxM)^T*B(KxN)
// ---------------------------------------------------------------------------
template<int MODE>
__global__ __launch_bounds__(256) void k_gemm(
    const float* __restrict__ A0, int lda, long long sAo, long long sAi,
    const float* __restrict__ B0, int ldb, long long sBo, long long sBi,
    float* __restrict__ C0, int ldc, long long sCo, long long sCi,
    const float* __restrict__ W0, long long sWo, long long sWi,
    const float* __restrict__ U0, long long sUo, long long sUi,
    const float* __restrict__ V0, long long sVo, long long sVi,
    const float* __restrict__ bias,
    int M, int N, int K, int zdiv)
{
  const int z = blockIdx.z, zo = z / zdiv, zi = z % zdiv;
  const float* A = A0 + zo*sAo + zi*sAi;
  const float* B = B0 + zo*sBo + zi*sBi;
  float* C = C0 + zo*sCo + zi*sCi;
  const float* Wv = W0 ? (W0 + zo*sWo + zi*sWi) : nullptr;
  const float* U  = U0 ? (U0 + zo*sUo + zi*sUi) : nullptr;
  const float* V  = V0 ? (V0 + zo*sVo + zi*sVi) : nullptr;

  __shared__ float As[16][68];
  __shared__ float Bs[16][68];
  const int mb = blockIdx.y*64, nb = blockIdx.x*64;
  const int tid = threadIdx.x;
  const int tx = tid & 15, ty = tid >> 4;
  const bool ISMAX = (MODE==3 || MODE==5);

  float acc[4][4];
  #pragma unroll
  for (int i=0;i<4;i++)
    #pragma unroll
    for (int j=0;j<4;j++) acc[i][j] = ISMAX ? -INFINITY : 0.f;

  for (int kt = 0; kt < K; kt += 16) {
    // ---- stage A ----
    if (MODE <= 3) {              // A is M x K row-major
      int ka = tid & 15, ma = tid >> 4;
      #pragma unroll
      for (int q=0;q<4;q++){
        int m = ma + q*16;
        float v = 0.f;
        if (mb+m < M && kt+ka < K){
          v = A[(size_t)(mb+m)*lda + kt+ka];
          if (MODE==1 && Wv){ float w = Wv[kt+ka]; v *= w*w; }
        }
        As[ka][m] = v;
      }
    } else {                      // A is K x M row-major (aTb)
      int ma = tid & 63, ka = tid >> 6;
      #pragma unroll
      for (int q=0;q<4;q++){
        int k = ka + q*4;
        float v = 0.f;
        if (kt+k < K && mb+ma < M) v = A[(size_t)(kt+k)*lda + mb+ma];
        As[k][ma] = v;
      }
    }
    // ---- stage B ----
    if (MODE <= 1) {              // B is N x K row-major (B^T gemm)
      int kb = tid & 15, nbi = tid >> 4;
      #pragma unroll
      for (int q=0;q<4;q++){
        int n = nbi + q*16;
        float v = 0.f;
        if (nb+n < N && kt+kb < K) v = B[(size_t)(nb+n)*ldb + kt+kb];
        Bs[kb][n] = v;
      }
    } else {                      // B is K x N row-major
      int nbi = tid & 63, kb = tid >> 6;
      #pragma unroll
      for (int q=0;q<4;q++){
        int k = kb + q*4;
        float v = 0.f;
        if (kt+k < K && nb+nbi < N) v = B[(size_t)(kt+k)*ldb + nb+nbi];
        Bs[k][nbi] = v;
      }
    }
    __syncthreads();
    #pragma unroll
    for (int k=0;k<16;k++){
      float a[4], bv[4];
      #pragma unroll
      for (int i=0;i<4;i++) a[i] = As[k][ty*4+i];
      #pragma unroll
      for (int j=0;j<4;j++) bv[j] = Bs[k][tx*4+j];
      #pragma unroll
      for (int i=0;i<4;i++)
        #pragma unroll
        for (int j=0;j<4;j++){
          if (ISMAX) acc[i][j] = fmaxf(acc[i][j], a[i]*bv[j]);
          else       acc[i][j] += a[i]*bv[j];
        }
    }
    __syncthreads();
  }
  // ---- epilogue ----
  #pragma unroll
  for (int i=0;i<4;i++){
    int m = mb + ty*4 + i;
    if (m >= M) continue;
    #pragma unroll
    for (int j=0;j<4;j++){
      int n = nb + tx*4 + j;
      if (n >= N) continue;
      float v = acc[i][j];
      if (MODE==0){ if (bias) v += bias[n]; }
      else if (MODE==1){ v = v / dsmall(U[m]*V[n]); }
      else if (MODE==2 || MODE==4){ v = v / dsmall(U[m]); }
      C[(size_t)m*ldc + n] = v;
    }
  }
}

// ---------------------------------------------------------------------------
// LSTM scan v3: 8 WGs per direction, LDS-resident weight slice, 8 seqs
// batched. Grid = 16 (dir = bx>>3, wg = bx&7). 256 threads.
// WG wg owns h indices [wg*32, wg*32+32).
// Thread (kc=tid>>5, gq=tid&31): 8 seqs x 4 gate-cols x 32 k per step.
// Sync: per-WG flag in its own 128B line (no RMW serialization) + 8 parallel
// acquire polls. 2-parity Hbuf: producer of parity p for step t+1 first
// observed all flags >= t+1, which are only posted after every WG finished
// reloading parity p from step t-1 -> no clobber, max skew 1 step.
// PRE: (8*256,1024) per dir. WT: (256,1024) = Whh^T per dir.
// Hbuf: [dir][parity][256 j][8 s]. flg: [dir*8+wg]*32 ints (zeroed).
// HSo: (8,256,512) [seq][t][dir*256+h] or null. HTo: (8dirseq,256) or null.
// ---------------------------------------------------------------------------
__global__ __launch_bounds__(256) void k_scan3(
    const float* __restrict__ PREf, const float* __restrict__ PREb,
    const float* __restrict__ WTf, const float* __restrict__ WTb,
    float* __restrict__ Hbuf, int* __restrict__ flg,
    float* __restrict__ HSo, float* __restrict__ HTo)
{
  const int wg = blockIdx.x & 7;
  const int d  = blockIdx.x >> 3;
  const float* PRE = d ? PREb : PREf;
  const float* WT  = d ? WTb  : WTf;
  float* Hb = Hbuf + (size_t)d*2*2048;
  int* fl = flg + d*8*32;

  __shared__ float Wl[256][128];     // 128 KB  Wl[k][gt*32+j]
  __shared__ float hl[256][8];       // 8 KB    hl[k][s]
  __shared__ float red[4][32][33];   // 16.5 KB red[kp][s*4+cc][gq] (padded)

  const int tid = threadIdx.x;
  // stage weight slice into LDS (once)
  for (int e = tid; e < 256*128; e += 256) {
    int k = e >> 7, c = e & 127;
    Wl[k][c] = WT[(size_t)k*1024 + (c>>5)*256 + wg*32 + (c&31)];
  }
  for (int e = tid; e < 2048; e += 256) ((float*)hl)[e] = 0.f;
  __syncthreads();

  const int kc = tid >> 5;   // k-chunk 0..7 (32 k each)
  const int gq = tid & 31;   // gate-col quad
  const int as = tid >> 5;   // activation: seq 0..7
  const int aj = tid & 31;   // activation: h-col within slice
  float cst = 0.f;

  for (int tt = 0; tt < 256; ++tt) {
    const int t = d ? 255 - tt : tt;
    const int wp = tt & 1;

    // prefetch PRE for activation (latency hidden under matmul)
    const size_t pbase = ((size_t)(as*256 + t))*1024 + wg*32 + aj;
    const float pre0 = PRE[pbase];       const float pre1 = PRE[pbase + 256];
    const float pre2 = PRE[pbase + 512]; const float pre3 = PRE[pbase + 768];

    // ---- gate matmul: acc[s][cc] over 32 k of chunk kc ----
    float acc[8][4];
    #pragma unroll
    for (int s=0;s<8;s++){ acc[s][0]=0.f; acc[s][1]=0.f; acc[s][2]=0.f; acc[s][3]=0.f; }
    #pragma unroll 4
    for (int kk = 0; kk < 32; ++kk) {
      int k = kc*32 + kk;
      float4 wv = *(const float4*)&Wl[k][gq*4];
      float4 ha = *(const float4*)&hl[k][0];
      float4 hb = *(const float4*)&hl[k][4];
      acc[0][0] += ha.x*wv.x; acc[0][1] += ha.x*wv.y; acc[0][2] += ha.x*wv.z; acc[0][3] += ha.x*wv.w;
      acc[1][0] += ha.y*wv.x; acc[1][1] += ha.y*wv.y; acc[1][2] += ha.y*wv.z; acc[1][3] += ha.y*wv.w;
      acc[2][0] += ha.z*wv.x; acc[2][1] += ha.z*wv.y; acc[2][2] += ha.z*wv.z; acc[2][3] += ha.z*wv.w;
      acc[3][0] += ha.w*wv.x; acc[3][1] += ha.w*wv.y; acc[3][2] += ha.w*wv.z; acc[3][3] += ha.w*wv.w;
      acc[4][0] += hb.x*wv.x; acc[4][1] += hb.x*wv.y; acc[4][2] += hb.x*wv.z; acc[4][3] += hb.x*wv.w;
      acc[5][0] += hb.y*wv.x; acc[5][1] += hb.y*wv.y; acc[5][2] += hb.y*wv.z; acc[5][3] += hb.y*wv.w;
      acc[6][0] += hb.z*wv.x; acc[6][1] += hb.z*wv.y; acc[6][2] += hb.z*wv.z; acc[6][3] += hb.z*wv.w;
      acc[7][0] += hb.w*wv.x; acc[7][1] += hb.w*wv.y; acc[7][2] += hb.w*wv.z; acc[7][3] += hb.w*wv.w;
    }
    // reduce kc-pairs (lanes l <-> l^32), stash to LDS (lane-stride-1, no conflicts)
    #pragma unroll
    for (int s=0;s<8;s++)
      #pragma unroll
      for (int c2=0;c2<4;c2++)
        acc[s][c2] += __shfl_xor(acc[s][c2], 32, 64);
    if ((tid & 32) == 0) {
      const int kp = kc >> 1;   // 0..3
      #pragma unroll
      for (int s=0;s<8;s++)
        #pragma unroll
        for (int c2=0;c2<4;c2++)
          red[kp][s*4+c2][gq] = acc[s][c2];
    }
    __syncthreads();

    // ---- activation + h/c update (all 256 threads) ----
    {
      float g[4];
      #pragma unroll
      for (int gt=0; gt<4; ++gt) {
        const int c = gt*32 + aj;
        const int gqq = c >> 2, cc = c & 3;
        const int ii = as*4 + cc;
        g[gt] = red[0][ii][gqq] + red[1][ii][gqq] + red[2][ii][gqq] + red[3][ii][gqq];
      }
      g[0] += pre0; g[1] += pre1; g[2] += pre2; g[3] += pre3;
      const float ig = sigf(g[0]), fg = sigf(g[1]), gg = tanhf(g[2]), og = sigf(g[3]);
      cst = fg*cst + ig*gg;
      const float h = og*tanhf(cst);
      __hip_atomic_store(&Hb[wp*2048 + (wg*32 + aj)*8 + as], h,
                         __ATOMIC_RELAXED, __HIP_MEMORY_SCOPE_AGENT);
      if (HSo) HSo[((size_t)(as*256 + t))*512 + d*256 + wg*32 + aj] = h;
      if (HTo && tt == 255) HTo[((size_t)(as*2 + d))*256 + wg*32 + aj] = h;
    }
    __syncthreads();  // drains all global stores (vmcnt(0) before barrier)

    // ---- cross-WG: post own flag (parallel lines), poll all 8 ----
    if (tid == 0)
      __hip_atomic_store(&fl[wg*32], tt+1, __ATOMIC_RELEASE, __HIP_MEMORY_SCOPE_AGENT);
    if (tid < 8)
      while (__hip_atomic_load(&fl[tid*32], __ATOMIC_ACQUIRE, __HIP_MEMORY_SCOPE_AGENT) < tt+1) {}
    __syncthreads();

    // ---- reload full h into LDS (coherent scalar loads) ----
    #pragma unroll
    for (int q=0;q<8;q++)
      ((float*)hl)[q*256 + tid] = __hip_atomic_load(&Hb[wp*2048 + q*256 + tid],
                                                    __ATOMIC_RELAXED, __HIP_MEMORY_SCOPE_AGENT);
    __syncthreads();
  }
}

// ---------------------------------------------------------------------------
// Row L2 norms of the 4096 (seq,dir,i) hidden rows.
// ---------------------------------------------------------------------------
__global__ __launch_bounds__(256) void k_rownorm(const float* __restrict__ HS_,
                                                 float* __restrict__ NORM_){
  int r = blockIdx.x*4 + (threadIdx.x >> 6);
  int lane = threadIdx.x & 63;
  int seq = r >> 9, d = (r >> 8) & 1, i = r & 255;
  const float* row = HS_ + ((size_t)(seq*256 + i))*512 + d*256;
  float s = 0.f;
  #pragma unroll
  for (int q=0;q<4;q++){ float v = row[lane + 64*q]; s += v*v; }
  for (int off=32; off; off>>=1) s += __shfl_xor(s, off, 64);
  if (lane == 0) NORM_[r] = sqrtf(s);
}

// ---------------------------------------------------------------------------
// Row sum+max reduction (cols elements per row, 4 rows/block)
// ---------------------------------------------------------------------------
__global__ __launch_bounds__(256) void k_rowred(const float* __restrict__ in,
                                                float* __restrict__ osum,
                                                float* __restrict__ omax, int cols){
  int r = blockIdx.x*4 + (threadIdx.x >> 6);
  int lane = threadIdx.x & 63;
  const float* row = in + (size_t)r*cols;
  float s = 0.f, m = -INFINITY;
  for (int cidx=lane; cidx<cols; cidx+=64){ float v=row[cidx]; s += v; m = fmaxf(m,v); }
  for (int off=32; off; off>>=1){ s += __shfl_xor(s,off,64); m = fmaxf(m, __shfl_xor(m,off,64)); }
  if (lane == 0){ if (osum) osum[r] = s; if (omax) omax[r] = m; }
}

// Column sum+max reduction over nrows, 256 cols, one block per z.
__global__ __launch_bounds__(256) void k_colred(const float* __restrict__ in0, long long zstride,
                                                int nrows, int ld,
                                                float* __restrict__ osum, float* __restrict__ omax){
  const float* in = in0 + (size_t)blockIdx.z*zstride;
  int j = threadIdx.x;
  float s = 0.f, m = -INFINITY;
  for (int r=0;r<nrows;r++){ float v = in[(size_t)r*ld + j]; s += v; m = fmaxf(m,v); }
  if (osum) osum[blockIdx.z*256 + j] = s;
  if (omax) omax[blockIdx.z*256 + j] = m;
}

// ---------------------------------------------------------------------------
// Weighted norms for pairwise matching: out[side][d][b][l][i]
// ---------------------------------------------------------------------------
__global__ __launch_bounds__(256) void k_wnorm(const float* __restrict__ HS_,
                                               const float* __restrict__ w3, const float* __restrict__ w4,
                                               float* __restrict__ WN1_, float* __restrict__ WN2_){
  int rid = blockIdx.x*4 + (threadIdx.x >> 6);
  int lane = threadIdx.x & 63;
  int side = rid / 20480; int rem = rid % 20480;
  int d = rem / 10240; int rem2 = rem % 10240;
  int b = rem2 / 2560; int l = (rem2 / 256) % 10; int i = rem2 & 255;
  int seq = side ? 4+b : b;
  const float* row = HS_ + ((size_t)(seq*256 + i))*512 + d*256;
  const float* w = (d ? w4 : w3) + l*256;
  float s = 0.f;
  #pragma unroll
  for (int q=0;q<4;q++){ float wv = w[lane+64*q]; float v = row[lane+64*q]; s += wv*wv*v*v; }
  for (int off=32; off; off>>=1) s += __shfl_xor(s, off, 64);
  if (lane == 0) (side ? WN2_ : WN1_)[rem] = sqrtf(s);
}

// ---------------------------------------------------------------------------
// Assemble mv rows (62 channels) incl. the 40 mp_match channels.
// Block per (side,b,i); 4 waves = 4 (vec,w) pairs.
// ---------------------------------------------------------------------------
__global__ __launch_bounds__(256) void k_mv(
    const float* __restrict__ HS_, const float* __restrict__ MEANH_, const float* __restrict__ MEANP_,
    const float* __restrict__ XH_, const float* __restrict__ XP_,
    const float* __restrict__ RS_, const float* __restrict__ RMAX_,
    const float* __restrict__ CS_, const float* __restrict__ CMAX_,
    const float* __restrict__ MMR_, const float* __restrict__ MMC_,
    const float* __restrict__ w5, const float* __restrict__ w6,
    const float* __restrict__ w7, const float* __restrict__ w8,
    float* __restrict__ MV_)
{
  const int blk = blockIdx.x;
  const int side = blk >> 10, b = (blk >> 8) & 3, i = blk & 255;
  const int wv = threadIdx.x >> 6, lane = threadIdx.x & 63;
  float* mvrow = MV_ + (size_t)blk*62;

  if (threadIdx.x == 0){
    const float* rmax = side ? CMAX_ : RMAX_;
    const float* rsum = side ? CS_   : RS_;
    mvrow[0] = rmax[b*256 + i];              // att_fw max
    mvrow[1] = rsum[b*256 + i] * (1.f/256.f);// att_fw mean
  }
  if (threadIdx.x < 20){
    int dd = threadIdx.x / 10, l = threadIdx.x % 10;
    const float* mm = side ? MMC_ : MMR_;
    mvrow[2 + dd*10 + l] = mm[dd*10240 + (b*10 + l)*256 + i];
  }
  const int d = wv & 1;                      // pairs 0,2 fw; 1,3 bw
  const int seq = side ? 4+b : b;
  const float* arow = HS_ + ((size_t)(seq*256 + i))*512 + d*256;
  const float* Mside = side ? MEANP_ : MEANH_;
  const float* Xside = side ? XP_ : XH_;
  const float* brow = (wv < 2 ? Mside : Xside) + (size_t)d*262144 + (size_t)b*65536 + (size_t)i*256;
  const float* wp = (wv==0) ? w5 : (wv==1) ? w6 : (wv==2) ? w7 : w8;

  float av[4], bv[4];
  #pragma unroll
  for (int q=0;q<4;q++){ av[q] = arow[lane+64*q]; bv[q] = brow[lane+64*q]; }
  for (int l=0;l<10;l++){
    const float* wrow = wp + l*256;
    float s1=0.f, s2=0.f, s3=0.f;
    #pragma unroll
    for (int q=0;q<4;q++){
      float w = wrow[lane+64*q]; float w2v = w*w;
      s1 += w2v*av[q]*bv[q]; s2 += w2v*av[q]*av[q]; s3 += w2v*bv[q]*bv[q];
    }
    for (int off=32; off; off>>=1){
      s1 += __shfl_xor(s1,off,64); s2 += __shfl_xor(s2,off,64); s3 += __shfl_xor(s3,off,64);
    }
    if (lane == 0) mvrow[22 + wv*10 + l] = s1 / fmaxf(sqrtf(s2)*sqrtf(s3), EPSV);
  }
}

// ---------------------------------------------------------------------------
// Mean over time of left/right: XM[b][side*300+d]
// ---------------------------------------------------------------------------
__global__ void k_means(const float* __restrict__ L, const float* __restrict__ R,
                        float* __restrict__ XM){
  int b = blockIdx.x & 3, sideR = blockIdx.x >> 2;
  const float* src = sideR ? R : L;
  int dch = threadIdx.x;
  if (dch >= 300) return;
  float s = 0.f;
  for (int t=0;t<256;t++) s += src[((size_t)(b*256 + t))*300 + dch];
  XM[b*600 + sideR*300 + dch] = s*(1.f/256.f);
}

// ---------------------------------------------------------------------------
// Head: fc1 (tanh), fc2
// ---------------------------------------------------------------------------
__global__ __launch_bounds__(512) void k_fc1(const float* __restrict__ HT_,
                                             const float* __restrict__ XM,
                                             const float* __restrict__ W1T,
                                             const float* __restrict__ b1,
                                             float* __restrict__ X2){
  __shared__ float x[1626];
  int b = blockIdx.x, t = threadIdx.x;
  if (t < 256){
    x[t]       = HT_[(b*2+0)*256 + t];
    x[256+t]   = HT_[(b*2+1)*256 + t];
    x[512+t]   = HT_[((4+b)*2+0)*256 + t];
    x[768+t]   = HT_[((4+b)*2+1)*256 + t];
  }
  if (t == 0){ x[1024] = 0.5f; x[1025] = 0.5f; }
  if (t < 300){ x[1026+t] = XM[b*600 + t]; x[1326+t] = XM[b*600 + 300 + t]; }
  __syncthreads();
  float acc = b1[t];
  for (int k=0;k<1626;k++) acc += x[k]*W1T[(size_t)k*512 + t];
  X2[b*512 + t] = tanhf(acc);
}

__global__ void k_fc2(const float* __restrict__ X2, const float* __restrict__ W2,
                      const float* __restrict__ b2, float* __restrict__ out){
  int b = blockIdx.x, o = threadIdx.x;
  if (o >= 22) return;
  float acc = b2[o];
  const float* xr = X2 + b*512;
  const float* wr = W2 + (size_t)o*512;
  for (int k=0;k<512;k++) acc += xr[k]*wr[k];
  out[b*22 + o] = acc;
}

// ---------------------------------------------------------------------------
extern "C" void kernel_launch(void* const* d_in, const int* in_sizes, int n_in,
                              void* d_out, int out_size, void* d_ws, size_t ws_size,
                              hipStream_t stream) {
  const float* left  = (const float*)d_in[0];
  const float* right = (const float*)d_in[1];
  const float* cWihF = (const float*)d_in[2];
  const float* cWhhF = (const float*)d_in[3];
  const float* cbF   = (const float*)d_in[4];
  const float* cWihB = (const float*)d_in[5];
  const float* cWhhB = (const float*)d_in[6];
  const float* cbB   = (const float*)d_in[7];
  const float* aWihF = (const float*)d_in[8];
  const float* aWhhF = (const float*)d_in[9];
  const float* abF   = (const float*)d_in[10];
  const float* aWihB = (const float*)d_in[11];
  const float* aWhhB = (const float*)d_in[12];
  const float* abB   = (const float*)d_in[13];
  const float* w3 = (const float*)d_in[14];
  const float* w4 = (const float*)d_in[15];
  const float* w5 = (const float*)d_in[16];
  const float* w6 = (const float*)d_in[17];
  const float* w7 = (const float*)d_in[18];
  const float* w8 = (const float*)d_in[19];
  const float* fc1W = (const float*)d_in[20];
  const float* fc1b = (const float*)d_in[21];
  const float* fc2W = (const float*)d_in[22];
  const float* fc2b = (const float*)d_in[23];
  float* out = (float*)d_out;
  float* ws = (float*)d_ws;

  // workspace layout (floats)
  float* WT    = ws;                 // 4 * 262144  (ctx_f, ctx_b, agg_f, agg_b)
  float* PREf  = ws + 1048576;       // 2097152
  float* PREb  = ws + 3145728;       // 2097152
  float* HS    = ws + 5242880;       // 1048576  (8,256,512)
  float* NORM  = ws + 6291456;       // 4096     [(seq*2+d)*256+i]
  float* ATT   = ws + 6295552;       // 524288   [d][b][i][j]
  float* RS    = ws + 6819840;       // 2048     [(d*4+b)*256+i]
  float* RMAX  = ws + 6821888;       // 2048
  float* CS    = ws + 6823936;       // 2048
  float* CMAX  = ws + 6825984;       // 2048
  float* MEANH = ws + 6828032;       // 524288   [d][b][i][h]
  float* MEANP = ws + 7352320;       // 524288   [d][b][j][h]
  float* XH    = ws + 7876608;       // 524288
  float* XP    = ws + 8400896;       // 524288
  float* WN1   = ws + 8925184;       // 20480    [d][b][l][i]
  float* WN2   = ws + 8945664;       // 20480
  float* MM    = ws + 8966144;       // 2621440  [b][l][i][j] (per dir, reused)
  float* MMR   = ws + 11587584;      // 20480    [d][b][l][i]
  float* MMC   = ws + 11608064;      // 20480
  float* MV    = ws + 11628544;      // 126976   (2048,62)
  float* HT    = ws + 11755520;      // 4096     [(seq*2+d)*256+j]
  float* XM    = ws + 11759616;      // 2400
  float* X2    = ws + 11762016;      // 2048
  float* W1T   = ws + 11764064;      // 832512

  // scan exchange buffers live in the (idle-during-scans) MM region
  float* HXB = MM;                   // 8192 floats: [dir][parity][256][8]
  int*   FLG = (int*)(MM + 8192);    // 512 ints:   [dir*8+wg]*32

  // 1. transposes
  k_transpose<<<dim3(8,32),  dim3(32,32), 0, stream>>>(cWhhF, WT + 0,      1024, 256);
  k_transpose<<<dim3(8,32),  dim3(32,32), 0, stream>>>(cWhhB, WT + 262144, 1024, 256);
  k_transpose<<<dim3(8,32),  dim3(32,32), 0, stream>>>(aWhhF, WT + 524288, 1024, 256);
  k_transpose<<<dim3(8,32),  dim3(32,32), 0, stream>>>(aWhhB, WT + 786432, 1024, 256);
  k_transpose<<<dim3(51,16), dim3(32,32), 0, stream>>>(fc1W, W1T, 512, 1626);

  // 2. ctx input projections (x @ Wih^T + b)
  k_gemm<0><<<dim3(16,16,1),256,0,stream>>>(left, 300,0,0,  cWihF,300,0,0,  PREf,           1024,0,0,
      nullptr,0,0, nullptr,0,0, nullptr,0,0, cbF, 1024,1024,300, 1);
  k_gemm<0><<<dim3(16,16,1),256,0,stream>>>(right,300,0,0,  cWihF,300,0,0,  PREf+1048576,   1024,0,0,
      nullptr,0,0, nullptr,0,0, nullptr,0,0, cbF, 1024,1024,300, 1);
  k_gemm<0><<<dim3(16,16,1),256,0,stream>>>(left, 300,0,0,  cWihB,300,0,0,  PREb,           1024,0,0,
      nullptr,0,0, nullptr,0,0, nullptr,0,0, cbB, 1024,1024,300, 1);
  k_gemm<0><<<dim3(16,16,1),256,0,stream>>>(right,300,0,0,  cWihB,300,0,0,  PREb+1048576,   1024,0,0,
      nullptr,0,0, nullptr,0,0, nullptr,0,0, cbB, 1024,1024,300, 1);

  // 3. ctx scan (8 WGs/dir, LDS-resident weights, flag sync)
  hipMemsetAsync(FLG, 0, 512*sizeof(int), stream);
  k_scan3<<<16,256,0,stream>>>(PREf, PREb, WT, WT+262144, HXB, FLG, HS, nullptr);

  // 4. row norms
  k_rownorm<<<1024,256,0,stream>>>(HS, NORM);

  // 5. att (cosine matrix), z = d*4+b
  k_gemm<1><<<dim3(4,4,8),256,0,stream>>>(HS,512,256,131072,  HS+524288,512,256,131072,
      ATT,256,262144,65536,  nullptr,0,0,  NORM,256,512,  NORM+2048,256,512,
      nullptr, 256,256,256, 4);

  // 6-7. att reductions
  k_rowred<<<512,256,0,stream>>>(ATT, RS, RMAX, 256);
  k_colred<<<dim3(1,1,8),256,0,stream>>>(ATT, 65536, 256, 256, CS, CMAX);

  // 8. attentive means and maxes
  k_gemm<2><<<dim3(4,4,8),256,0,stream>>>(ATT,256,262144,65536,  HS+524288,512,256,131072,
      MEANH,256,262144,65536,  nullptr,0,0,  RS,1024,256,  nullptr,0,0, nullptr, 256,256,256, 4);
  k_gemm<4><<<dim3(4,4,8),256,0,stream>>>(ATT,256,262144,65536,  HS,512,256,131072,
      MEANP,256,262144,65536,  nullptr,0,0,  CS,1024,256,  nullptr,0,0, nullptr, 256,256,256, 4);
  k_gemm<3><<<dim3(4,4,8),256,0,stream>>>(ATT,256,262144,65536,  HS+524288,512,256,131072,
      XH,256,262144,65536,  nullptr,0,0,  nullptr,0,0,  nullptr,0,0, nullptr, 256,256,256, 4);
  k_gemm<5><<<dim3(4,4,8),256,0,stream>>>(ATT,256,262144,65536,  HS,512,256,131072,
      XP,256,262144,65536,  nullptr,0,0,  nullptr,0,0,  nullptr,0,0, nullptr, 256,256,256, 4);

  // 9. weighted norms
  k_wnorm<<<10240,256,0,stream>>>(HS, w3, w4, WN1, WN2);

  // 10-13. pairwise mm (fw then bw, buffer reused), z = b*10+l
  k_gemm<1><<<dim3(4,4,40),256,0,stream>>>(HS,512,131072,0,  HS+524288,512,131072,0,
      MM,256,655360,65536,  w3,0,256,  WN1,2560,256,  WN2,2560,256,
      nullptr, 256,256,256, 10);
  k_rowred<<<2560,256,0,stream>>>(MM, nullptr, MMR, 256);
  k_colred<<<dim3(1,1,40),256,0,stream>>>(MM, 65536, 256, 256, nullptr, MMC);
  k_gemm<1><<<dim3(4,4,40),256,0,stream>>>(HS+256,512,131072,0,  HS+524288+256,512,131072,0,
      MM,256,655360,65536,  w4,0,256,  WN1+10240,2560,256,  WN2+10240,2560,256,
      nullptr, 256,256,256, 10);
  k_rowred<<<2560,256,0,stream>>>(MM, nullptr, MMR+10240, 256);
  k_colred<<<dim3(1,1,40),256,0,stream>>>(MM, 65536, 256, 256, nullptr, MMC+10240);

  // 14. assemble mv (2048 rows x 62)
  k_mv<<<2048,256,0,stream>>>(HS, MEANH, MEANP, XH, XP, RS, RMAX, CS, CMAX,
                              MMR, MMC, w5, w6, w7, w8, MV);

  // 15. agg projections
  k_gemm<0><<<dim3(16,32,1),256,0,stream>>>(MV,62,0,0,  aWihF,62,0,0,  PREf,1024,0,0,
      nullptr,0,0, nullptr,0,0, nullptr,0,0, abF, 2048,1024,62, 1);
  k_gemm<0><<<dim3(16,32,1),256,0,stream>>>(MV,62,0,0,  aWihB,62,0,0,  PREb,1024,0,0,
      nullptr,0,0, nullptr,0,0, nullptr,0,0, abB, 2048,1024,62, 1);

  // 16. agg scan (keep only final h)
  hipMemsetAsync(FLG, 0, 512*sizeof(int), stream);
  k_scan3<<<16,256,0,stream>>>(PREf, PREb, WT+524288, WT+786432, HXB, FLG, nullptr, HT);

  // 17-19. head
  k_means<<<8,320,0,stream>>>(left, right, XM);
  k_fc1<<<4,512,0,stream>>>(HT, XM, W1T, fc1b, X2);
  k_fc2<<<4,64,0,stream>>>(X2, fc2W, fc2b, out);
}

// Round 4
// 3975.319 us; speedup vs baseline: 1.0475x; 1.0475x over previous
//
#include <hip/hip_runtime.h>
#include <hip/hip_bf16.h>
#include <math.h>

#define EPSV 1e-8f

__device__ __forceinline__ float dsmall(float d){ return d > EPSV ? d : EPSV; }
__device__ __forceinline__ float sigf(float x){ return 1.f/(1.f+expf(-x)); }

// ---------------------------------------------------------------------------
// Transpose: W (R x C) -> WT (C x R)
// ---------------------------------------------------------------------------
__global__ __launch_bounds__(1024) void k_transpose(const float* __restrict__ W,
                                                    float* __restrict__ WT, int R, int C){
  __shared__ float t[32][33];
  int rb = blockIdx.y*32, cb = blockIdx.x*32;
  int r = rb + threadIdx.y, c = cb + threadIdx.x;
  if (r < R && c < C) t[threadIdx.y][threadIdx.x] = W[(size_t)r*C + c];
  __syncthreads();
  int rr = cb + threadIdx.y, cc = rb + threadIdx.x;
  if (rr < C && cc < R) WT[(size_t)rr*R + cc] = t[threadIdx.x][threadIdx.y];
}

// ---------------------------------------------------------------------------
// Generic z-batched tiled GEMM-like kernel. 64x64 tile, 256 thr, 4x4/thread.
// MODE 0: C=A(MxK)@B(NxK)^T + bias[n]
// MODE 1: C=(A*wscale^2)(MxK)@B(NxK)^T / dsmall(U[m]*V[n])
// MODE 2: C=A(MxK)@B(KxN) / dsmall(U[m])
// MODE 3: C=max_k A(MxK)*B(KxN)
// MODE 4: C=A(KxM)^T@B(KxN) / dsmall(U[m])
// MODE 5: C=max_k A(KxM)^T*B(KxN)
// ---------------------------------------------------------------------------
template<int MODE>
__global__ __launch_bounds__(256) void k_gemm(
    const float* __restrict__ A0, int lda, long long sAo, long long sAi,
    const float* __restrict__ B0, int ldb, long long sBo, long long sBi,
    float* __restrict__ C0, int ldc, long long sCo, long long sCi,
    const float* __restrict__ W0, long long sWo, long long sWi,
    const float* __restrict__ U0, long long sUo, long long sUi,
    const float* __restrict__ V0, long long sVo, long long sVi,
    const float* __restrict__ bias,
    int M, int N, int K, int zdiv)
{
  const int z = blockIdx.z, zo = z / zdiv, zi = z % zdiv;
  const float* A = A0 + zo*sAo + zi*sAi;
  const float* B = B0 + zo*sBo + zi*sBi;
  float* C = C0 + zo*sCo + zi*sCi;
  const float* Wv = W0 ? (W0 + zo*sWo + zi*sWi) : nullptr;
  const float* U  = U0 ? (U0 + zo*sUo + zi*sUi) : nullptr;
  const float* V  = V0 ? (V0 + zo*sVo + zi*sVi) : nullptr;

  __shared__ float As[16][68];
  __shared__ float Bs[16][68];
  const int mb = blockIdx.y*64, nb = blockIdx.x*64;
  const int tid = threadIdx.x;
  const int tx = tid & 15, ty = tid >> 4;
  const bool ISMAX = (MODE==3 || MODE==5);

  float acc[4][4];
  #pragma unroll
  for (int i=0;i<4;i++)
    #pragma unroll
    for (int j=0;j<4;j++) acc[i][j] = ISMAX ? -INFINITY : 0.f;

  for (int kt = 0; kt < K; kt += 16) {
    // ---- stage A ----
    if (MODE <= 3) {              // A is M x K row-major
      int ka = tid & 15, ma = tid >> 4;
      #pragma unroll
      for (int q=0;q<4;q++){
        int m = ma + q*16;
        float v = 0.f;
        if (mb+m < M && kt+ka < K){
          v = A[(size_t)(mb+m)*lda + kt+ka];
          if (MODE==1 && Wv){ float w = Wv[kt+ka]; v *= w*w; }
        }
        As[ka][m] = v;
      }
    } else {                      // A is K x M row-major (aTb)
      int ma = tid & 63, ka = tid >> 6;
      #pragma unroll
      for (int q=0;q<4;q++){
        int k = ka + q*4;
        float v = 0.f;
        if (kt+k < K && mb+ma < M) v = A[(size_t)(kt+k)*lda + mb+ma];
        As[k][ma] = v;
      }
    }
    // ---- stage B ----
    if (MODE <= 1) {              // B is N x K row-major (B^T gemm)
      int kb = tid & 15, nbi = tid >> 4;
      #pragma unroll
      for (int q=0;q<4;q++){
        int n = nbi + q*16;
        float v = 0.f;
        if (nb+n < N && kt+kb < K) v = B[(size_t)(nb+n)*ldb + kt+kb];
        Bs[kb][n] = v;
      }
    } else {                      // B is K x N row-major
      int nbi = tid & 63, kb = tid >> 6;
      #pragma unroll
      for (int q=0;q<4;q++){
        int k = kb + q*4;
        float v = 0.f;
        if (kt+k < K && nb+nbi < N) v = B[(size_t)(kt+k)*ldb + nb+nbi];
        Bs[k][nbi] = v;
      }
    }
    __syncthreads();
    #pragma unroll
    for (int k=0;k<16;k++){
      float a[4], bv[4];
      #pragma unroll
      for (int i=0;i<4;i++) a[i] = As[k][ty*4+i];
      #pragma unroll
      for (int j=0;j<4;j++) bv[j] = Bs[k][tx*4+j];
      #pragma unroll
      for (int i=0;i<4;i++)
        #pragma unroll
        for (int j=0;j<4;j++){
          if (ISMAX) acc[i][j] = fmaxf(acc[i][j], a[i]*bv[j]);
          else       acc[i][j] += a[i]*bv[j];
        }
    }
    __syncthreads();
  }
  // ---- epilogue ----
  #pragma unroll
  for (int i=0;i<4;i++){
    int m = mb + ty*4 + i;
    if (m >= M) continue;
    #pragma unroll
    for (int j=0;j<4;j++){
      int n = nb + tx*4 + j;
      if (n >= N) continue;
      float v = acc[i][j];
      if (MODE==0){ if (bias) v += bias[n]; }
      else if (MODE==1){ v = v / dsmall(U[m]*V[n]); }
      else if (MODE==2 || MODE==4){ v = v / dsmall(U[m]); }
      C[(size_t)m*ldc + n] = v;
    }
  }
}

// ---------------------------------------------------------------------------
// LSTM scan v4: 8 WGs per direction, LDS-resident weight slice, 8 seqs
// batched. Grid = 64; xcd = bx&7 (round-robin block->XCD): teams for dir 0/1
// use xcd 0/1 so each team's exchange lines live in ONE L2 domain. Blocks
// with xcd>1 exit. slot wg = bx>>3. Correctness is placement-agnostic
// (agent-scope ops); placement only affects latency.
// WG wg owns h indices [wg*32, wg*32+32). 256 threads.
// Sync: per-WG flag in its own 128B line, release store after barrier-drained
// data stores; peers poll all 8 flags RELAXED (no per-iter invalidate).
// 2-parity Hbuf; skew argument: flag t+2 certifies parity-wp reload of step t
// done (program order), so overwrite at t+2 is safe.
// PRE: (8*256,1024) per dir. WT: (256,1024) = Whh^T per dir.
// Hbuf: [dir][parity][256 j][8 s]. flg: [dir*8+wg]*32 ints (zeroed).
// HSo: (8,256,512) [seq][t][dir*256+h] or null. HTo: (8dirseq,256) or null.
// ---------------------------------------------------------------------------
__global__ __launch_bounds__(256) void k_scan4(
    const float* __restrict__ PREf, const float* __restrict__ PREb,
    const float* __restrict__ WTf, const float* __restrict__ WTb,
    float* __restrict__ Hbuf, int* __restrict__ flg,
    float* __restrict__ HSo, float* __restrict__ HTo)
{
  const int xcd = blockIdx.x & 7;
  if (xcd > 1) return;
  const int d  = xcd;
  const int wg = blockIdx.x >> 3;
  const float* PRE = d ? PREb : PREf;
  const float* WT  = d ? WTb  : WTf;
  float* Hb = Hbuf + (size_t)d*2*2048;
  int* fl = flg + d*8*32;

  __shared__ float Wl[256][128];     // 128 KB  Wl[k][gt*32+j]
  __shared__ float hl[256][8];       // 8 KB    hl[k][s]
  __shared__ float red[4][32][40];   // 20 KB   red[kp][s*4+cc][gq] (bank-disjoint)

  const int tid = threadIdx.x;
  // stage weight slice into LDS (once)
  for (int e = tid; e < 256*128; e += 256) {
    int k = e >> 7, c = e & 127;
    Wl[k][c] = WT[(size_t)k*1024 + (c>>5)*256 + wg*32 + (c&31)];
  }
  for (int e = tid; e < 2048; e += 256) ((float*)hl)[e] = 0.f;
  __syncthreads();

  const int kc = tid >> 5;   // k-chunk 0..7 (32 k each)
  const int gq = tid & 31;   // gate-col quad
  const int as = tid >> 5;   // activation: seq 0..7
  const int aj = tid & 31;   // activation: h-col within slice
  float cst = 0.f;

  for (int tt = 0; tt < 256; ++tt) {
    const int t = d ? 255 - tt : tt;
    const int wp = tt & 1;

    // prefetch PRE for activation (latency hidden under matmul)
    const size_t pbase = ((size_t)(as*256 + t))*1024 + wg*32 + aj;
    const float pre0 = PRE[pbase];       const float pre1 = PRE[pbase + 256];
    const float pre2 = PRE[pbase + 512]; const float pre3 = PRE[pbase + 768];

    // ---- gate matmul: acc[s][cc] over 32 k of chunk kc ----
    float acc[8][4];
    #pragma unroll
    for (int s=0;s<8;s++){ acc[s][0]=0.f; acc[s][1]=0.f; acc[s][2]=0.f; acc[s][3]=0.f; }
    #pragma unroll 4
    for (int kk = 0; kk < 32; ++kk) {
      int k = kc*32 + kk;
      float4 wv = *(const float4*)&Wl[k][gq*4];
      float4 ha = *(const float4*)&hl[k][0];
      float4 hb = *(const float4*)&hl[k][4];
      acc[0][0] += ha.x*wv.x; acc[0][1] += ha.x*wv.y; acc[0][2] += ha.x*wv.z; acc[0][3] += ha.x*wv.w;
      acc[1][0] += ha.y*wv.x; acc[1][1] += ha.y*wv.y; acc[1][2] += ha.y*wv.z; acc[1][3] += ha.y*wv.w;
      acc[2][0] += ha.z*wv.x; acc[2][1] += ha.z*wv.y; acc[2][2] += ha.z*wv.z; acc[2][3] += ha.z*wv.w;
      acc[3][0] += ha.w*wv.x; acc[3][1] += ha.w*wv.y; acc[3][2] += ha.w*wv.z; acc[3][3] += ha.w*wv.w;
      acc[4][0] += hb.x*wv.x; acc[4][1] += hb.x*wv.y; acc[4][2] += hb.x*wv.z; acc[4][3] += hb.x*wv.w;
      acc[5][0] += hb.y*wv.x; acc[5][1] += hb.y*wv.y; acc[5][2] += hb.y*wv.z; acc[5][3] += hb.y*wv.w;
      acc[6][0] += hb.z*wv.x; acc[6][1] += hb.z*wv.y; acc[6][2] += hb.z*wv.z; acc[6][3] += hb.z*wv.w;
      acc[7][0] += hb.w*wv.x; acc[7][1] += hb.w*wv.y; acc[7][2] += hb.w*wv.z; acc[7][3] += hb.w*wv.w;
    }
    // reduce kc-pairs (lanes l <-> l^32), stash to LDS (lane-stride-1 writes)
    #pragma unroll
    for (int s=0;s<8;s++)
      #pragma unroll
      for (int c2=0;c2<4;c2++)
        acc[s][c2] += __shfl_xor(acc[s][c2], 32, 64);
    if ((tid & 32) == 0) {
      const int kp = kc >> 1;   // 0..3
      #pragma unroll
      for (int s=0;s<8;s++)
        #pragma unroll
        for (int c2=0;c2<4;c2++)
          red[kp][s*4+c2][gq] = acc[s][c2];
    }
    __syncthreads();

    // ---- activation + h/c update (all 256 threads) ----
    {
      float g[4];
      #pragma unroll
      for (int gt=0; gt<4; ++gt) {
        const int c = gt*32 + aj;
        const int gqq = c >> 2, cc = c & 3;
        const int ii = as*4 + cc;
        g[gt] = red[0][ii][gqq] + red[1][ii][gqq] + red[2][ii][gqq] + red[3][ii][gqq];
      }
      g[0] += pre0; g[1] += pre1; g[2] += pre2; g[3] += pre3;
      const float ig = sigf(g[0]), fg = sigf(g[1]), gg = tanhf(g[2]), og = sigf(g[3]);
      cst = fg*cst + ig*gg;
      const float h = og*tanhf(cst);
      __hip_atomic_store(&Hb[wp*2048 + (wg*32 + aj)*8 + as], h,
                         __ATOMIC_RELAXED, __HIP_MEMORY_SCOPE_AGENT);
      if (HSo) HSo[((size_t)(as*256 + t))*512 + d*256 + wg*32 + aj] = h;
      if (HTo && tt == 255) HTo[((size_t)(as*2 + d))*256 + wg*32 + aj] = h;
    }
    __syncthreads();  // drains all global stores (vmcnt(0) before barrier)

    // ---- cross-WG: post own flag (own 128B line), poll all 8 RELAXED ----
    if (tid == 0)
      __hip_atomic_store(&fl[wg*32], tt+1, __ATOMIC_RELEASE, __HIP_MEMORY_SCOPE_AGENT);
    if (tid < 8)
      while (__hip_atomic_load(&fl[tid*32], __ATOMIC_RELAXED, __HIP_MEMORY_SCOPE_AGENT) < tt+1) {}
    __syncthreads();

    // ---- reload full h into LDS ----
    #pragma unroll
    for (int q=0;q<8;q++)
      ((float*)hl)[q*256 + tid] = __hip_atomic_load(&Hb[wp*2048 + q*256 + tid],
                                                    __ATOMIC_RELAXED, __HIP_MEMORY_SCOPE_AGENT);
    __syncthreads();
  }
}

// ---------------------------------------------------------------------------
// Row L2 norms of the 4096 (seq,dir,i) hidden rows.
// ---------------------------------------------------------------------------
__global__ __launch_bounds__(256) void k_rownorm(const float* __restrict__ HS_,
                                                 float* __restrict__ NORM_){
  int r = blockIdx.x*4 + (threadIdx.x >> 6);
  int lane = threadIdx.x & 63;
  int seq = r >> 9, d = (r >> 8) & 1, i = r & 255;
  const float* row = HS_ + ((size_t)(seq*256 + i))*512 + d*256;
  float s = 0.f;
  #pragma unroll
  for (int q=0;q<4;q++){ float v = row[lane + 64*q]; s += v*v; }
  for (int off=32; off; off>>=1) s += __shfl_xor(s, off, 64);
  if (lane == 0) NORM_[r] = sqrtf(s);
}

// ---------------------------------------------------------------------------
// Row sum+max reduction (cols elements per row, 4 rows/block)
// ---------------------------------------------------------------------------
__global__ __launch_bounds__(256) void k_rowred(const float* __restrict__ in,
                                                float* __restrict__ osum,
                                                float* __restrict__ omax, int cols){
  int r = blockIdx.x*4 + (threadIdx.x >> 6);
  int lane = threadIdx.x & 63;
  const float* row = in + (size_t)r*cols;
  float s = 0.f, m = -INFINITY;
  for (int cidx=lane; cidx<cols; cidx+=64){ float v=row[cidx]; s += v; m = fmaxf(m,v); }
  for (int off=32; off; off>>=1){ s += __shfl_xor(s,off,64); m = fmaxf(m, __shfl_xor(m,off,64)); }
  if (lane == 0){ if (osum) osum[r] = s; if (omax) omax[r] = m; }
}

// Column sum+max reduction over nrows, 256 cols, one block per z.
__global__ __launch_bounds__(256) void k_colred(const float* __restrict__ in0, long long zstride,
                                                int nrows, int ld,
                                                float* __restrict__ osum, float* __restrict__ omax){
  const float* in = in0 + (size_t)blockIdx.z*zstride;
  int j = threadIdx.x;
  float s = 0.f, m = -INFINITY;
  for (int r=0;r<nrows;r++){ float v = in[(size_t)r*ld + j]; s += v; m = fmaxf(m,v); }
  if (osum) osum[blockIdx.z*256 + j] = s;
  if (omax) omax[blockIdx.z*256 + j] = m;
}

// ---------------------------------------------------------------------------
// Weighted norms for pairwise matching: out[side][d][b][l][i]
// ---------------------------------------------------------------------------
__global__ __launch_bounds__(256) void k_wnorm(const float* __restrict__ HS_,
                                               const float* __restrict__ w3, const float* __restrict__ w4,
                                               float* __restrict__ WN1_, float* __restrict__ WN2_){
  int rid = blockIdx.x*4 + (threadIdx.x >> 6);
  int lane = threadIdx.x & 63;
  int side = rid / 20480; int rem = rid % 20480;
  int d = rem / 10240; int rem2 = rem % 10240;
  int b = rem2 / 2560; int l = (rem2 / 256) % 10; int i = rem2 & 255;
  int seq = side ? 4+b : b;
  const float* row = HS_ + ((size_t)(seq*256 + i))*512 + d*256;
  const float* w = (d ? w4 : w3) + l*256;
  float s = 0.f;
  #pragma unroll
  for (int q=0;q<4;q++){ float wv = w[lane+64*q]; float v = row[lane+64*q]; s += wv*wv*v*v; }
  for (int off=32; off; off>>=1) s += __shfl_xor(s, off, 64);
  if (lane == 0) (side ? WN2_ : WN1_)[rem] = sqrtf(s);
}

// ---------------------------------------------------------------------------
// Assemble mv rows (62 channels) incl. the 40 mp_match channels.
// Block per (side,b,i); 4 waves = 4 (vec,w) pairs.
// ---------------------------------------------------------------------------
__global__ __launch_bounds__(256) void k_mv(
    const float* __restrict__ HS_, const float* __restrict__ MEANH_, const float* __restrict__ MEANP_,
    const float* __restrict__ XH_, const float* __restrict__ XP_,
    const float* __restrict__ RS_, const float* __restrict__ RMAX_,
    const float* __restrict__ CS_, const float* __restrict__ CMAX_,
    const float* __restrict__ MMR_, const float* __restrict__ MMC_,
    const float* __restrict__ w5, const float* __restrict__ w6,
    const float* __restrict__ w7, const float* __restrict__ w8,
    float* __restrict__ MV_)
{
  const int blk = blockIdx.x;
  const int side = blk >> 10, b = (blk >> 8) & 3, i = blk & 255;
  const int wv = threadIdx.x >> 6, lane = threadIdx.x & 63;
  float* mvrow = MV_ + (size_t)blk*62;

  if (threadIdx.x == 0){
    const float* rmax = side ? CMAX_ : RMAX_;
    const float* rsum = side ? CS_   : RS_;
    mvrow[0] = rmax[b*256 + i];              // att_fw max
    mvrow[1] = rsum[b*256 + i] * (1.f/256.f);// att_fw mean
  }
  if (threadIdx.x < 20){
    int dd = threadIdx.x / 10, l = threadIdx.x % 10;
    const float* mm = side ? MMC_ : MMR_;
    mvrow[2 + dd*10 + l] = mm[dd*10240 + (b*10 + l)*256 + i];
  }
  const int d = wv & 1;                      // pairs 0,2 fw; 1,3 bw
  const int seq = side ? 4+b : b;
  const float* arow = HS_ + ((size_t)(seq*256 + i))*512 + d*256;
  const float* Mside = side ? MEANP_ : MEANH_;
  const float* Xside = side ? XP_ : XH_;
  const float* brow = (wv < 2 ? Mside : Xside) + (size_t)d*262144 + (size_t)b*65536 + (size_t)i*256;
  const float* wp = (wv==0) ? w5 : (wv==1) ? w6 : (wv==2) ? w7 : w8;

  float av[4], bv[4];
  #pragma unroll
  for (int q=0;q<4;q++){ av[q] = arow[lane+64*q]; bv[q] = brow[lane+64*q]; }
  for (int l=0;l<10;l++){
    const float* wrow = wp + l*256;
    float s1=0.f, s2=0.f, s3=0.f;
    #pragma unroll
    for (int q=0;q<4;q++){
      float w = wrow[lane+64*q]; float w2v = w*w;
      s1 += w2v*av[q]*bv[q]; s2 += w2v*av[q]*av[q]; s3 += w2v*bv[q]*bv[q];
    }
    for (int off=32; off; off>>=1){
      s1 += __shfl_xor(s1,off,64); s2 += __shfl_xor(s2,off,64); s3 += __shfl_xor(s3,off,64);
    }
    if (lane == 0) mvrow[22 + wv*10 + l] = s1 / fmaxf(sqrtf(s2)*sqrtf(s3), EPSV);
  }
}

// ---------------------------------------------------------------------------
// Mean over time of left/right: XM[b][side*300+d]
// ---------------------------------------------------------------------------
__global__ void k_means(const float* __restrict__ L, const float* __restrict__ R,
                        float* __restrict__ XM){
  int b = blockIdx.x & 3, sideR = blockIdx.x >> 2;
  const float* src = sideR ? R : L;
  int dch = threadIdx.x;
  if (dch >= 300) return;
  float s = 0.f;
  for (int t=0;t<256;t++) s += src[((size_t)(b*256 + t))*300 + dch];
  XM[b*600 + sideR*300 + dch] = s*(1.f/256.f);
}

// ---------------------------------------------------------------------------
// Head: fc1 (tanh), fc2
// ---------------------------------------------------------------------------
__global__ __launch_bounds__(512) void k_fc1(const float* __restrict__ HT_,
                                             const float* __restrict__ XM,
                                             const float* __restrict__ W1T,
                                             const float* __restrict__ b1,
                                             float* __restrict__ X2){
  __shared__ float x[1626];
  int b = blockIdx.x, t = threadIdx.x;
  if (t < 256){
    x[t]       = HT_[(b*2+0)*256 + t];
    x[256+t]   = HT_[(b*2+1)*256 + t];
    x[512+t]   = HT_[((4+b)*2+0)*256 + t];
    x[768+t]   = HT_[((4+b)*2+1)*256 + t];
  }
  if (t == 0){ x[1024] = 0.5f; x[1025] = 0.5f; }
  if (t < 300){ x[1026+t] = XM[b*600 + t]; x[1326+t] = XM[b*600 + 300 + t]; }
  __syncthreads();
  float acc = b1[t];
  for (int k=0;k<1626;k++) acc += x[k]*W1T[(size_t)k*512 + t];
  X2[b*512 + t] = tanhf(acc);
}

__global__ void k_fc2(const float* __restrict__ X2, const float* __restrict__ W2,
                      const float* __restrict__ b2, float* __restrict__ out){
  int b = blockIdx.x, o = threadIdx.x;
  if (o >= 22) return;
  float acc = b2[o];
  const float* xr = X2 + b*512;
  const float* wr = W2 + (size_t)o*512;
  for (int k=0;k<512;k++) acc += xr[k]*wr[k];
  out[b*22 + o] = acc;
}

// ---------------------------------------------------------------------------
extern "C" void kernel_launch(void* const* d_in, const int* in_sizes, int n_in,
                              void* d_out, int out_size, void* d_ws, size_t ws_size,
                              hipStream_t stream) {
  const float* left  = (const float*)d_in[0];
  const float* right = (const float*)d_in[1];
  const float* cWihF = (const float*)d_in[2];
  const float* cWhhF = (const float*)d_in[3];
  const float* cbF   = (const float*)d_in[4];
  const float* cWihB = (const float*)d_in[5];
  const float* cWhhB = (const float*)d_in[6];
  const float* cbB   = (const float*)d_in[7];
  const float* aWihF = (const float*)d_in[8];
  const float* aWhhF = (const float*)d_in[9];
  const float* abF   = (const float*)d_in[10];
  const float* aWihB = (const float*)d_in[11];
  const float* aWhhB = (const float*)d_in[12];
  const float* abB   = (const float*)d_in[13];
  const float* w3 = (const float*)d_in[14];
  const float* w4 = (const float*)d_in[15];
  const float* w5 = (const float*)d_in[16];
  const float* w6 = (const float*)d_in[17];
  const float* w7 = (const float*)d_in[18];
  const float* w8 = (const float*)d_in[19];
  const float* fc1W = (const float*)d_in[20];
  const float* fc1b = (const float*)d_in[21];
  const float* fc2W = (const float*)d_in[22];
  const float* fc2b = (const float*)d_in[23];
  float* out = (float*)d_out;
  float* ws = (float*)d_ws;

  // workspace layout (floats)
  float* WT    = ws;                 // 4 * 262144  (ctx_f, ctx_b, agg_f, agg_b)
  float* PREf  = ws + 1048576;       // 2097152
  float* PREb  = ws + 3145728;       // 2097152
  float* HS    = ws + 5242880;       // 1048576  (8,256,512)
  float* NORM  = ws + 6291456;       // 4096     [(seq*2+d)*256+i]
  float* ATT   = ws + 6295552;       // 524288   [d][b][i][j]
  float* RS    = ws + 6819840;       // 2048     [(d*4+b)*256+i]
  float* RMAX  = ws + 6821888;       // 2048
  float* CS    = ws + 6823936;       // 2048
  float* CMAX  = ws + 6825984;       // 2048
  float* MEANH = ws + 6828032;       // 524288   [d][b][i][h]
  float* MEANP = ws + 7352320;       // 524288   [d][b][j][h]
  float* XH    = ws + 7876608;       // 524288
  float* XP    = ws + 8400896;       // 524288
  float* WN1   = ws + 8925184;       // 20480    [d][b][l][i]
  float* WN2   = ws + 8945664;       // 20480
  float* MM    = ws + 8966144;       // 2621440  [b][l][i][j] (per dir, reused)
  float* MMR   = ws + 11587584;      // 20480    [d][b][l][i]
  float* MMC   = ws + 11608064;      // 20480
  float* MV    = ws + 11628544;      // 126976   (2048,62)
  float* HT    = ws + 11755520;      // 4096     [(seq*2+d)*256+j]
  float* XM    = ws + 11759616;      // 2400
  float* X2    = ws + 11762016;      // 2048
  float* W1T   = ws + 11764064;      // 832512

  // scan exchange buffers live in the (idle-during-scans) MM region
  float* HXB = MM;                   // 8192 floats: [dir][parity][256][8]
  int*   FLG = (int*)(MM + 8192);    // 512 ints:   [dir*8+wg]*32

  // 1. transposes
  k_transpose<<<dim3(8,32),  dim3(32,32), 0, stream>>>(cWhhF, WT + 0,      1024, 256);
  k_transpose<<<dim3(8,32),  dim3(32,32), 0, stream>>>(cWhhB, WT + 262144, 1024, 256);
  k_transpose<<<dim3(8,32),  dim3(32,32), 0, stream>>>(aWhhF, WT + 524288, 1024, 256);
  k_transpose<<<dim3(8,32),  dim3(32,32), 0, stream>>>(aWhhB, WT + 786432, 1024, 256);
  k_transpose<<<dim3(51,16), dim3(32,32), 0, stream>>>(fc1W, W1T, 512, 1626);

  // 2. ctx input projections (x @ Wih^T + b)
  k_gemm<0><<<dim3(16,16,1),256,0,stream>>>(left, 300,0,0,  cWihF,300,0,0,  PREf,           1024,0,0,
      nullptr,0,0, nullptr,0,0, nullptr,0,0, cbF, 1024,1024,300, 1);
  k_gemm<0><<<dim3(16,16,1),256,0,stream>>>(right,300,0,0,  cWihF,300,0,0,  PREf+1048576,   1024,0,0,
      nullptr,0,0, nullptr,0,0, nullptr,0,0, cbF, 1024,1024,300, 1);
  k_gemm<0><<<dim3(16,16,1),256,0,stream>>>(left, 300,0,0,  cWihB,300,0,0,  PREb,           1024,0,0,
      nullptr,0,0, nullptr,0,0, nullptr,0,0, cbB, 1024,1024,300, 1);
  k_gemm<0><<<dim3(16,16,1),256,0,stream>>>(right,300,0,0,  cWihB,300,0,0,  PREb+1048576,   1024,0,0,
      nullptr,0,0, nullptr,0,0, nullptr,0,0, cbB, 1024,1024,300, 1);

  // 3. ctx scan (8 WGs/dir on one XCD each, LDS-resident weights)
  hipMemsetAsync(FLG, 0, 512*sizeof(int), stream);
  k_scan4<<<64,256,0,stream>>>(PREf, PREb, WT, WT+262144, HXB, FLG, HS, nullptr);

  // 4. row norms
  k_rownorm<<<1024,256,0,stream>>>(HS, NORM);

  // 5. att (cosine matrix), z = d*4+b
  k_gemm<1><<<dim3(4,4,8),256,0,stream>>>(HS,512,256,131072,  HS+524288,512,256,131072,
      ATT,256,262144,65536,  nullptr,0,0,  NORM,256,512,  NORM+2048,256,512,
      nullptr, 256,256,256, 4);

  // 6-7. att reductions
  k_rowred<<<512,256,0,stream>>>(ATT, RS, RMAX, 256);
  k_colred<<<dim3(1,1,8),256,0,stream>>>(ATT, 65536, 256, 256, CS, CMAX);

  // 8. attentive means and maxes
  k_gemm<2><<<dim3(4,4,8),256,0,stream>>>(ATT,256,262144,65536,  HS+524288,512,256,131072,
      MEANH,256,262144,65536,  nullptr,0,0,  RS,1024,256,  nullptr,0,0, nullptr, 256,256,256, 4);
  k_gemm<4><<<dim3(4,4,8),256,0,stream>>>(ATT,256,262144,65536,  HS,512,256,131072,
      MEANP,256,262144,65536,  nullptr,0,0,  CS,1024,256,  nullptr,0,0, nullptr, 256,256,256, 4);
  k_gemm<3><<<dim3(4,4,8),256,0,stream>>>(ATT,256,262144,65536,  HS+524288,512,256,131072,
      XH,256,262144,65536,  nullptr,0,0,  nullptr,0,0,  nullptr,0,0, nullptr, 256,256,256, 4);
  k_gemm<5><<<dim3(4,4,8),256,0,stream>>>(ATT,256,262144,65536,  HS,512,256,131072,
      XP,256,262144,65536,  nullptr,0,0,  nullptr,0,0,  nullptr,0,0, nullptr, 256,256,256, 4);

  // 9. weighted norms
  k_wnorm<<<10240,256,0,stream>>>(HS, w3, w4, WN1, WN2);

  // 10-13. pairwise mm (fw then bw, buffer reused), z = b*10+l
  k_gemm<1><<<dim3(4,4,40),256,0,stream>>>(HS,512,131072,0,  HS+524288,512,131072,0,
      MM,256,655360,65536,  w3,0,256,  WN1,2560,256,  WN2,2560,256,
      nullptr, 256,256,256, 10);
  k_rowred<<<2560,256,0,stream>>>(MM, nullptr, MMR, 256);
  k_colred<<<dim3(1,1,40),256,0,stream>>>(MM, 65536, 256, 256, nullptr, MMC);
  k_gemm<1><<<dim3(4,4,40),256,0,stream>>>(HS+256,512,131072,0,  HS+524288+256,512,131072,0,
      MM,256,655360,65536,  w4,0,256,  WN1+10240,2560,256,  WN2+10240,2560,256,
      nullptr, 256,256,256, 10);
  k_rowred<<<2560,256,0,stream>>>(MM, nullptr, MMR+10240, 256);
  k_colred<<<dim3(1,1,40),256,0,stream>>>(MM, 65536, 256, 256, nullptr, MMC+10240);

  // 14. assemble mv (2048 rows x 62)
  k_mv<<<2048,256,0,stream>>>(HS, MEANH, MEANP, XH, XP, RS, RMAX, CS, CMAX,
                              MMR, MMC, w5, w6, w7, w8, MV);

  // 15. agg projections
  k_gemm<0><<<dim3(16,32,1),256,0,stream>>>(MV,62,0,0,  aWihF,62,0,0,  PREf,1024,0,0,
      nullptr,0,0, nullptr,0,0, nullptr,0,0, abF, 2048,1024,62, 1);
  k_gemm<0><<<dim3(16,32,1),256,0,stream>>>(MV,62,0,0,  aWihB,62,0,0,  PREb,1024,0,0,
      nullptr,0,0, nullptr,0,0, nullptr,0,0, abB, 2048,1024,62, 1);

  // 16. agg scan (keep only final h)
  hipMemsetAsync(FLG, 0, 512*sizeof(int), stream);
  k_scan4<<<64,256,0,stream>>>(PREf, PREb, WT+524288, WT+786432, HXB, FLG, nullptr, HT);

  // 17-19. head
  k_means<<<8,320,0,stream>>>(left, right, XM);
  k_fc1<<<4,512,0,stream>>>(HT, XM, W1T, fc1b, X2);
  k_fc2<<<4,64,0,stream>>>(X2, fc2W, fc2b, out);
}

// Round 5
// 3275.621 us; speedup vs baseline: 1.2713x; 1.2136x over previous
//
#include <hip/hip_runtime.h>
#include <hip/hip_bf16.h>
#include <math.h>

#define EPSV 1e-8f

__device__ __forceinline__ float dsmall(float d){ return d > EPSV ? d : EPSV; }
__device__ __forceinline__ float sigf(float x){ return 1.f/(1.f+expf(-x)); }

// ---------------------------------------------------------------------------
// Transpose: W (R x C) -> WT (C x R)
// ---------------------------------------------------------------------------
__global__ __launch_bounds__(1024) void k_transpose(const float* __restrict__ W,
                                                    float* __restrict__ WT, int R, int C){
  __shared__ float t[32][33];
  int rb = blockIdx.y*32, cb = blockIdx.x*32;
  int r = rb + threadIdx.y, c = cb + threadIdx.x;
  if (r < R && c < C) t[threadIdx.y][threadIdx.x] = W[(size_t)r*C + c];
  __syncthreads();
  int rr = cb + threadIdx.y, cc = rb + threadIdx.x;
  if (rr < C && cc < R) WT[(size_t)rr*R + cc] = t[threadIdx.x][threadIdx.y];
}

// ---------------------------------------------------------------------------
// Generic z-batched tiled GEMM-like kernel. 64x64 tile, 256 thr, 4x4/thread.
// MODE 0: C=A(MxK)@B(NxK)^T + bias[n]
// MODE 1: C=(A*wscale^2)(MxK)@B(NxK)^T / dsmall(U[m]*V[n])
// MODE 2: C=A(MxK)@B(KxN) / dsmall(U[m])
// MODE 3: C=max_k A(MxK)*B(KxN)
// MODE 4: C=A(KxM)^T@B(KxN) / dsmall(U[m])
// MODE 5: C=max_k A(KxM)^T*B(KxN)
// ---------------------------------------------------------------------------
template<int MODE>
__global__ __launch_bounds__(256) void k_gemm(
    const float* __restrict__ A0, int lda, long long sAo, long long sAi,
    const float* __restrict__ B0, int ldb, long long sBo, long long sBi,
    float* __restrict__ C0, int ldc, long long sCo, long long sCi,
    const float* __restrict__ W0, long long sWo, long long sWi,
    const float* __restrict__ U0, long long sUo, long long sUi,
    const float* __restrict__ V0, long long sVo, long long sVi,
    const float* __restrict__ bias,
    int M, int N, int K, int zdiv)
{
  const int z = blockIdx.z, zo = z / zdiv, zi = z % zdiv;
  const float* A = A0 + zo*sAo + zi*sAi;
  const float* B = B0 + zo*sBo + zi*sBi;
  float* C = C0 + zo*sCo + zi*sCi;
  const float* Wv = W0 ? (W0 + zo*sWo + zi*sWi) : nullptr;
  const float* U  = U0 ? (U0 + zo*sUo + zi*sUi) : nullptr;
  const float* V  = V0 ? (V0 + zo*sVo + zi*sVi) : nullptr;

  __shared__ float As[16][68];
  __shared__ float Bs[16][68];
  const int mb = blockIdx.y*64, nb = blockIdx.x*64;
  const int tid = threadIdx.x;
  const int tx = tid & 15, ty = tid >> 4;
  const bool ISMAX = (MODE==3 || MODE==5);

  float acc[4][4];
  #pragma unroll
  for (int i=0;i<4;i++)
    #pragma unroll
    for (int j=0;j<4;j++) acc[i][j] = ISMAX ? -INFINITY : 0.f;

  for (int kt = 0; kt < K; kt += 16) {
    // ---- stage A ----
    if (MODE <= 3) {              // A is M x K row-major
      int ka = tid & 15, ma = tid >> 4;
      #pragma unroll
      for (int q=0;q<4;q++){
        int m = ma + q*16;
        float v = 0.f;
        if (mb+m < M && kt+ka < K){
          v = A[(size_t)(mb+m)*lda + kt+ka];
          if (MODE==1 && Wv){ float w = Wv[kt+ka]; v *= w*w; }
        }
        As[ka][m] = v;
      }
    } else {                      // A is K x M row-major (aTb)
      int ma = tid & 63, ka = tid >> 6;
      #pragma unroll
      for (int q=0;q<4;q++){
        int k = ka + q*4;
        float v = 0.f;
        if (kt+k < K && mb+ma < M) v = A[(size_t)(kt+k)*lda + mb+ma];
        As[k][ma] = v;
      }
    }
    // ---- stage B ----
    if (MODE <= 1) {              // B is N x K row-major (B^T gemm)
      int kb = tid & 15, nbi = tid >> 4;
      #pragma unroll
      for (int q=0;q<4;q++){
        int n = nbi + q*16;
        float v = 0.f;
        if (nb+n < N && kt+kb < K) v = B[(size_t)(nb+n)*ldb + kt+kb];
        Bs[kb][n] = v;
      }
    } else {                      // B is K x N row-major
      int nbi = tid & 63, kb = tid >> 6;
      #pragma unroll
      for (int q=0;q<4;q++){
        int k = kb + q*4;
        float v = 0.f;
        if (kt+k < K && nb+nbi < N) v = B[(size_t)(kt+k)*ldb + nb+nbi];
        Bs[k][nbi] = v;
      }
    }
    __syncthreads();
    #pragma unroll
    for (int k=0;k<16;k++){
      float a[4], bv[4];
      #pragma unroll
      for (int i=0;i<4;i++) a[i] = As[k][ty*4+i];
      #pragma unroll
      for (int j=0;j<4;j++) bv[j] = Bs[k][tx*4+j];
      #pragma unroll
      for (int i=0;i<4;i++)
        #pragma unroll
        for (int j=0;j<4;j++){
          if (ISMAX) acc[i][j] = fmaxf(acc[i][j], a[i]*bv[j]);
          else       acc[i][j] += a[i]*bv[j];
        }
    }
    __syncthreads();
  }
  // ---- epilogue ----
  #pragma unroll
  for (int i=0;i<4;i++){
    int m = mb + ty*4 + i;
    if (m >= M) continue;
    #pragma unroll
    for (int j=0;j<4;j++){
      int n = nb + tx*4 + j;
      if (n >= N) continue;
      float v = acc[i][j];
      if (MODE==0){ if (bias) v += bias[n]; }
      else if (MODE==1){ v = v / dsmall(U[m]*V[n]); }
      else if (MODE==2 || MODE==4){ v = v / dsmall(U[m]); }
      C[(size_t)m*ldc + n] = v;
    }
  }
}

// ---------------------------------------------------------------------------
// LSTM scan v5: 8 WGs/dir, Whh slice in VGPRs (static across steps), 8 seqs
// batched. Grid=64; active blocks: bx&7 in {0,1} = dir; wg = bx>>3.
// Thread (kc=tid>>5, gq=tid&31): holds weights wv[32] = W[kc*32+kk][gq*4+cc]
// in 128 VGPRs. Gate matmul reads h broadcast from LDS, weights from regs.
// Exchange: group kc consumes ONLY h-chunk kc -> per-half-wave poll of
// flag[kc] + 1KB fetch into its own hl rows (single reader=writer half-wave,
// no barrier). Own chunk written to hl during activation (covered by B2).
// 2-parity Hbuf, reuse distance 2: flag[c]=tt certifies WG c's parity-(tt-2)
// reads done (fetch<matmul<store program order) -> no clobber.
// PRE: (8*256,1024)/dir. WT: (256,1024)=Whh^T/dir.
// Hbuf: [dir][parity][256 j][8 s]. flg: [dir*8+wg]*32 ints (zeroed).
// HSo: (8,256,512) or null. HTo: (8,256) [(seq*2+d)*256+j] or null.
// ---------------------------------------------------------------------------
__global__ __launch_bounds__(256, 1) void k_scan5(
    const float* __restrict__ PREf, const float* __restrict__ PREb,
    const float* __restrict__ WTf, const float* __restrict__ WTb,
    float* __restrict__ Hbuf, int* __restrict__ flg,
    float* __restrict__ HSo, float* __restrict__ HTo)
{
  const int xcd = blockIdx.x & 7;
  if (xcd > 1) return;
  const int d  = xcd;
  const int wg = blockIdx.x >> 3;
  const float* PRE = d ? PREb : PREf;
  const float* WT  = d ? WTb  : WTf;
  float* Hb = Hbuf + (size_t)d*2*2048;
  int* fl = flg + d*8*32;

  __shared__ float hl[256][8];       // 8 KB   hl[k][s]; chunk c = rows [c*32,c*32+32)
  __shared__ float red[4][32][40];   // 20 KB  red[kp][s*4+cc][gq] (bank-disjoint)

  const int tid = threadIdx.x;
  const int kc = tid >> 5;   // k-chunk 0..7 (32 k each)
  const int gq = tid & 31;   // gate-col quad
  const int as = tid >> 5;   // activation: seq 0..7
  const int aj = tid & 31;   // activation: h-col within slice

  // stage weight slice into REGISTERS (static across all 256 steps)
  float4 wv[32];
  {
    const float* wbase = WT + (gq>>3)*256 + wg*32 + (gq&7)*4;
    #pragma unroll
    for (int kk=0; kk<32; ++kk)
      wv[kk] = *(const float4*)&wbase[(size_t)(kc*32+kk)*1024];
  }
  for (int e = tid; e < 2048; e += 256) ((float*)hl)[e] = 0.f;
  float cst = 0.f;
  __syncthreads();

  for (int tt = 0; tt < 256; ++tt) {
    const int t = d ? 255 - tt : tt;
    const int wp = tt & 1;          // parity this iteration stores (h_state(tt+1))
    const int sp = (tt + 1) & 1;    // parity holding h_state(tt) (stored at tt-1)

    // ---- per-half-wave fetch of remote chunk kc of h_state(tt) ----
    if (tt > 0 && kc != wg) {
      const int* flp = &fl[kc*32];
      while (__hip_atomic_load(flp, __ATOMIC_RELAXED, __HIP_MEMORY_SCOPE_AGENT) < tt)
        __builtin_amdgcn_s_sleep(1);
      const unsigned long long* srcu =
          (const unsigned long long*)&Hb[sp*2048 + kc*256 + gq*8];
      unsigned long long u0 = __hip_atomic_load(srcu+0, __ATOMIC_RELAXED, __HIP_MEMORY_SCOPE_AGENT);
      unsigned long long u1 = __hip_atomic_load(srcu+1, __ATOMIC_RELAXED, __HIP_MEMORY_SCOPE_AGENT);
      unsigned long long u2 = __hip_atomic_load(srcu+2, __ATOMIC_RELAXED, __HIP_MEMORY_SCOPE_AGENT);
      unsigned long long u3 = __hip_atomic_load(srcu+3, __ATOMIC_RELAXED, __HIP_MEMORY_SCOPE_AGENT);
      unsigned long long* dst = (unsigned long long*)&((float*)hl)[kc*256 + gq*8];
      dst[0] = u0; dst[1] = u1; dst[2] = u2; dst[3] = u3;
    }

    // prefetch PRE for activation (hidden under matmul)
    const size_t pbase = ((size_t)(as*256 + t))*1024 + wg*32 + aj;
    const float pre0 = PRE[pbase];       const float pre1 = PRE[pbase + 256];
    const float pre2 = PRE[pbase + 512]; const float pre3 = PRE[pbase + 768];

    // ---- gate matmul: acc[s][cc] over 32 k of chunk kc, weights in regs ----
    float acc[8][4];
    #pragma unroll
    for (int s=0;s<8;s++){ acc[s][0]=0.f; acc[s][1]=0.f; acc[s][2]=0.f; acc[s][3]=0.f; }
    #pragma unroll
    for (int kk = 0; kk < 32; ++kk) {
      const int k = kc*32 + kk;
      float4 ha = *(const float4*)&hl[k][0];
      float4 hb = *(const float4*)&hl[k][4];
      float4 w  = wv[kk];
      acc[0][0] += ha.x*w.x; acc[0][1] += ha.x*w.y; acc[0][2] += ha.x*w.z; acc[0][3] += ha.x*w.w;
      acc[1][0] += ha.y*w.x; acc[1][1] += ha.y*w.y; acc[1][2] += ha.y*w.z; acc[1][3] += ha.y*w.w;
      acc[2][0] += ha.z*w.x; acc[2][1] += ha.z*w.y; acc[2][2] += ha.z*w.z; acc[2][3] += ha.z*w.w;
      acc[3][0] += ha.w*w.x; acc[3][1] += ha.w*w.y; acc[3][2] += ha.w*w.z; acc[3][3] += ha.w*w.w;
      acc[4][0] += hb.x*w.x; acc[4][1] += hb.x*w.y; acc[4][2] += hb.x*w.z; acc[4][3] += hb.x*w.w;
      acc[5][0] += hb.y*w.x; acc[5][1] += hb.y*w.y; acc[5][2] += hb.y*w.z; acc[5][3] += hb.y*w.w;
      acc[6][0] += hb.z*w.x; acc[6][1] += hb.z*w.y; acc[6][2] += hb.z*w.z; acc[6][3] += hb.z*w.w;
      acc[7][0] += hb.w*w.x; acc[7][1] += hb.w*w.y; acc[7][2] += hb.w*w.z; acc[7][3] += hb.w*w.w;
    }
    // reduce kc-pairs (lanes l <-> l^32), stash to LDS (lane-stride-1 writes)
    #pragma unroll
    for (int s=0;s<8;s++)
      #pragma unroll
      for (int c2=0;c2<4;c2++)
        acc[s][c2] += __shfl_xor(acc[s][c2], 32, 64);
    if ((tid & 32) == 0) {
      const int kp = kc >> 1;   // 0..3
      #pragma unroll
      for (int s=0;s<8;s++)
        #pragma unroll
        for (int c2=0;c2<4;c2++)
          red[kp][s*4+c2][gq] = acc[s][c2];
    }
    __syncthreads();   // B1: red ready

    // ---- activation + h/c update (all 256 threads) ----
    float hreg;
    {
      float g[4];
      #pragma unroll
      for (int gt=0; gt<4; ++gt) {
        const int c = gt*32 + aj;
        const int gqq = c >> 2, cc = c & 3;
        const int ii = as*4 + cc;
        g[gt] = red[0][ii][gqq] + red[1][ii][gqq] + red[2][ii][gqq] + red[3][ii][gqq];
      }
      g[0] += pre0; g[1] += pre1; g[2] += pre2; g[3] += pre3;
      const float ig = sigf(g[0]), fg = sigf(g[1]), gg = tanhf(g[2]), og = sigf(g[3]);
      cst = fg*cst + ig*gg;
      hreg = og*tanhf(cst);
      // own chunk -> LDS directly (visible WG-wide after B2)
      hl[wg*32 + aj][as] = hreg;
      // publish to peers (L2)
      __hip_atomic_store(&Hb[wp*2048 + (wg*32 + aj)*8 + as], hreg,
                         __ATOMIC_RELAXED, __HIP_MEMORY_SCOPE_AGENT);
    }
    __syncthreads();   // B2: drains Hb stores (vmcnt(0)) + own-hl ds_writes

    // ---- post own flag (own 128B line); peers poll per-half-wave ----
    if (tid == 0)
      __hip_atomic_store(&fl[wg*32], tt+1, __ATOMIC_RELEASE, __HIP_MEMORY_SCOPE_AGENT);

    // ---- HSo/HTo stores OFF the critical path (drained by next B2) ----
    if (HSo) HSo[((size_t)(as*256 + t))*512 + d*256 + wg*32 + aj] = hreg;
    if (HTo && tt == 255) HTo[((size_t)(as*2 + d))*256 + wg*32 + aj] = hreg;
  }
}

// ---------------------------------------------------------------------------
// Row L2 norms of the 4096 (seq,dir,i) hidden rows.
// ---------------------------------------------------------------------------
__global__ __launch_bounds__(256) void k_rownorm(const float* __restrict__ HS_,
                                                 float* __restrict__ NORM_){
  int r = blockIdx.x*4 + (threadIdx.x >> 6);
  int lane = threadIdx.x & 63;
  int seq = r >> 9, d = (r >> 8) & 1, i = r & 255;
  const float* row = HS_ + ((size_t)(seq*256 + i))*512 + d*256;
  float s = 0.f;
  #pragma unroll
  for (int q=0;q<4;q++){ float v = row[lane + 64*q]; s += v*v; }
  for (int off=32; off; off>>=1) s += __shfl_xor(s, off, 64);
  if (lane == 0) NORM_[r] = sqrtf(s);
}

// ---------------------------------------------------------------------------
// Row sum+max reduction (cols elements per row, 4 rows/block)
// ---------------------------------------------------------------------------
__global__ __launch_bounds__(256) void k_rowred(const float* __restrict__ in,
                                                float* __restrict__ osum,
                                                float* __restrict__ omax, int cols){
  int r = blockIdx.x*4 + (threadIdx.x >> 6);
  int lane = threadIdx.x & 63;
  const float* row = in + (size_t)r*cols;
  float s = 0.f, m = -INFINITY;
  for (int cidx=lane; cidx<cols; cidx+=64){ float v=row[cidx]; s += v; m = fmaxf(m,v); }
  for (int off=32; off; off>>=1){ s += __shfl_xor(s,off,64); m = fmaxf(m, __shfl_xor(m,off,64)); }
  if (lane == 0){ if (osum) osum[r] = s; if (omax) omax[r] = m; }
}

// Column sum+max reduction over nrows, 256 cols, one block per z.
__global__ __launch_bounds__(256) void k_colred(const float* __restrict__ in0, long long zstride,
                                                int nrows, int ld,
                                                float* __restrict__ osum, float* __restrict__ omax){
  const float* in = in0 + (size_t)blockIdx.z*zstride;
  int j = threadIdx.x;
  float s = 0.f, m = -INFINITY;
  for (int r=0;r<nrows;r++){ float v = in[(size_t)r*ld + j]; s += v; m = fmaxf(m,v); }
  if (osum) osum[blockIdx.z*256 + j] = s;
  if (omax) omax[blockIdx.z*256 + j] = m;
}

// ---------------------------------------------------------------------------
// Weighted norms for pairwise matching: out[side][d][b][l][i]
// ---------------------------------------------------------------------------
__global__ __launch_bounds__(256) void k_wnorm(const float* __restrict__ HS_,
                                               const float* __restrict__ w3, const float* __restrict__ w4,
                                               float* __restrict__ WN1_, float* __restrict__ WN2_){
  int rid = blockIdx.x*4 + (threadIdx.x >> 6);
  int lane = threadIdx.x & 63;
  int side = rid / 20480; int rem = rid % 20480;
  int d = rem / 10240; int rem2 = rem % 10240;
  int b = rem2 / 2560; int l = (rem2 / 256) % 10; int i = rem2 & 255;
  int seq = side ? 4+b : b;
  const float* row = HS_ + ((size_t)(seq*256 + i))*512 + d*256;
  const float* w = (d ? w4 : w3) + l*256;
  float s = 0.f;
  #pragma unroll
  for (int q=0;q<4;q++){ float wv = w[lane+64*q]; float v = row[lane+64*q]; s += wv*wv*v*v; }
  for (int off=32; off; off>>=1) s += __shfl_xor(s, off, 64);
  if (lane == 0) (side ? WN2_ : WN1_)[rem] = sqrtf(s);
}

// ---------------------------------------------------------------------------
// Assemble mv rows (62 channels) incl. the 40 mp_match channels.
// Block per (side,b,i); 4 waves = 4 (vec,w) pairs.
// ---------------------------------------------------------------------------
__global__ __launch_bounds__(256) void k_mv(
    const float* __restrict__ HS_, const float* __restrict__ MEANH_, const float* __restrict__ MEANP_,
    const float* __restrict__ XH_, const float* __restrict__ XP_,
    const float* __restrict__ RS_, const float* __restrict__ RMAX_,
    const float* __restrict__ CS_, const float* __restrict__ CMAX_,
    const float* __restrict__ MMR_, const float* __restrict__ MMC_,
    const float* __restrict__ w5, const float* __restrict__ w6,
    const float* __restrict__ w7, const float* __restrict__ w8,
    float* __restrict__ MV_)
{
  const int blk = blockIdx.x;
  const int side = blk >> 10, b = (blk >> 8) & 3, i = blk & 255;
  const int wv = threadIdx.x >> 6, lane = threadIdx.x & 63;
  float* mvrow = MV_ + (size_t)blk*62;

  if (threadIdx.x == 0){
    const float* rmax = side ? CMAX_ : RMAX_;
    const float* rsum = side ? CS_   : RS_;
    mvrow[0] = rmax[b*256 + i];              // att_fw max
    mvrow[1] = rsum[b*256 + i] * (1.f/256.f);// att_fw mean
  }
  if (threadIdx.x < 20){
    int dd = threadIdx.x / 10, l = threadIdx.x % 10;
    const float* mm = side ? MMC_ : MMR_;
    mvrow[2 + dd*10 + l] = mm[dd*10240 + (b*10 + l)*256 + i];
  }
  const int d = wv & 1;                      // pairs 0,2 fw; 1,3 bw
  const int seq = side ? 4+b : b;
  const float* arow = HS_ + ((size_t)(seq*256 + i))*512 + d*256;
  const float* Mside = side ? MEANP_ : MEANH_;
  const float* Xside = side ? XP_ : XH_;
  const float* brow = (wv < 2 ? Mside : Xside) + (size_t)d*262144 + (size_t)b*65536 + (size_t)i*256;
  const float* wp = (wv==0) ? w5 : (wv==1) ? w6 : (wv==2) ? w7 : w8;

  float av[4], bv[4];
  #pragma unroll
  for (int q=0;q<4;q++){ av[q] = arow[lane+64*q]; bv[q] = brow[lane+64*q]; }
  for (int l=0;l<10;l++){
    const float* wrow = wp + l*256;
    float s1=0.f, s2=0.f, s3=0.f;
    #pragma unroll
    for (int q=0;q<4;q++){
      float w = wrow[lane+64*q]; float w2v = w*w;
      s1 += w2v*av[q]*bv[q]; s2 += w2v*av[q]*av[q]; s3 += w2v*bv[q]*bv[q];
    }
    for (int off=32; off; off>>=1){
      s1 += __shfl_xor(s1,off,64); s2 += __shfl_xor(s2,off,64); s3 += __shfl_xor(s3,off,64);
    }
    if (lane == 0) mvrow[22 + wv*10 + l] = s1 / fmaxf(sqrtf(s2)*sqrtf(s3), EPSV);
  }
}

// ---------------------------------------------------------------------------
// Mean over time of left/right: XM[b][side*300+d]
// ---------------------------------------------------------------------------
__global__ void k_means(const float* __restrict__ L, const float* __restrict__ R,
                        float* __restrict__ XM){
  int b = blockIdx.x & 3, sideR = blockIdx.x >> 2;
  const float* src = sideR ? R : L;
  int dch = threadIdx.x;
  if (dch >= 300) return;
  float s = 0.f;
  for (int t=0;t<256;t++) s += src[((size_t)(b*256 + t))*300 + dch];
  XM[b*600 + sideR*300 + dch] = s*(1.f/256.f);
}

// ---------------------------------------------------------------------------
// Head: fc1 (tanh), fc2
// ---------------------------------------------------------------------------
__global__ __launch_bounds__(512) void k_fc1(const float* __restrict__ HT_,
                                             const float* __restrict__ XM,
                                             const float* __restrict__ W1T,
                                             const float* __restrict__ b1,
                                             float* __restrict__ X2){
  __shared__ float x[1626];
  int b = blockIdx.x, t = threadIdx.x;
  if (t < 256){
    x[t]       = HT_[(b*2+0)*256 + t];
    x[256+t]   = HT_[(b*2+1)*256 + t];
    x[512+t]   = HT_[((4+b)*2+0)*256 + t];
    x[768+t]   = HT_[((4+b)*2+1)*256 + t];
  }
  if (t == 0){ x[1024] = 0.5f; x[1025] = 0.5f; }
  if (t < 300){ x[1026+t] = XM[b*600 + t]; x[1326+t] = XM[b*600 + 300 + t]; }
  __syncthreads();
  float acc = b1[t];
  for (int k=0;k<1626;k++) acc += x[k]*W1T[(size_t)k*512 + t];
  X2[b*512 + t] = tanhf(acc);
}

__global__ void k_fc2(const float* __restrict__ X2, const float* __restrict__ W2,
                      const float* __restrict__ b2, float* __restrict__ out){
  int b = blockIdx.x, o = threadIdx.x;
  if (o >= 22) return;
  float acc = b2[o];
  const float* xr = X2 + b*512;
  const float* wr = W2 + (size_t)o*512;
  for (int k=0;k<512;k++) acc += xr[k]*wr[k];
  out[b*22 + o] = acc;
}

// ---------------------------------------------------------------------------
extern "C" void kernel_launch(void* const* d_in, const int* in_sizes, int n_in,
                              void* d_out, int out_size, void* d_ws, size_t ws_size,
                              hipStream_t stream) {
  const float* left  = (const float*)d_in[0];
  const float* right = (const float*)d_in[1];
  const float* cWihF = (const float*)d_in[2];
  const float* cWhhF = (const float*)d_in[3];
  const float* cbF   = (const float*)d_in[4];
  const float* cWihB = (const float*)d_in[5];
  const float* cWhhB = (const float*)d_in[6];
  const float* cbB   = (const float*)d_in[7];
  const float* aWihF = (const float*)d_in[8];
  const float* aWhhF = (const float*)d_in[9];
  const float* abF   = (const float*)d_in[10];
  const float* aWihB = (const float*)d_in[11];
  const float* aWhhB = (const float*)d_in[12];
  const float* abB   = (const float*)d_in[13];
  const float* w3 = (const float*)d_in[14];
  const float* w4 = (const float*)d_in[15];
  const float* w5 = (const float*)d_in[16];
  const float* w6 = (const float*)d_in[17];
  const float* w7 = (const float*)d_in[18];
  const float* w8 = (const float*)d_in[19];
  const float* fc1W = (const float*)d_in[20];
  const float* fc1b = (const float*)d_in[21];
  const float* fc2W = (const float*)d_in[22];
  const float* fc2b = (const float*)d_in[23];
  float* out = (float*)d_out;
  float* ws = (float*)d_ws;

  // workspace layout (floats)
  float* WT    = ws;                 // 4 * 262144  (ctx_f, ctx_b, agg_f, agg_b)
  float* PREf  = ws + 1048576;       // 2097152
  float* PREb  = ws + 3145728;       // 2097152
  float* HS    = ws + 5242880;       // 1048576  (8,256,512)
  float* NORM  = ws + 6291456;       // 4096     [(seq*2+d)*256+i]
  float* ATT   = ws + 6295552;       // 524288   [d][b][i][j]
  float* RS    = ws + 6819840;       // 2048     [(d*4+b)*256+i]
  float* RMAX  = ws + 6821888;       // 2048
  float* CS    = ws + 6823936;       // 2048
  float* CMAX  = ws + 6825984;       // 2048
  float* MEANH = ws + 6828032;       // 524288   [d][b][i][h]
  float* MEANP = ws + 7352320;       // 524288   [d][b][j][h]
  float* XH    = ws + 7876608;       // 524288
  float* XP    = ws + 8400896;       // 524288
  float* WN1   = ws + 8925184;       // 20480    [d][b][l][i]
  float* WN2   = ws + 8945664;       // 20480
  float* MM    = ws + 8966144;       // 2621440  [b][l][i][j] (per dir, reused)
  float* MMR   = ws + 11587584;      // 20480    [d][b][l][i]
  float* MMC   = ws + 11608064;      // 20480
  float* MV    = ws + 11628544;      // 126976   (2048,62)
  float* HT    = ws + 11755520;      // 4096     [(seq*2+d)*256+j]
  float* XM    = ws + 11759616;      // 2400
  float* X2    = ws + 11762016;      // 2048
  float* W1T   = ws + 11764064;      // 832512

  // scan exchange buffers live in the (idle-during-scans) MM region
  float* HXB = MM;                   // 8192 floats: [dir][parity][256][8]
  int*   FLG = (int*)(MM + 8192);    // 512 ints:   [dir*8+wg]*32

  // 1. transposes
  k_transpose<<<dim3(8,32),  dim3(32,32), 0, stream>>>(cWhhF, WT + 0,      1024, 256);
  k_transpose<<<dim3(8,32),  dim3(32,32), 0, stream>>>(cWhhB, WT + 262144, 1024, 256);
  k_transpose<<<dim3(8,32),  dim3(32,32), 0, stream>>>(aWhhF, WT + 524288, 1024, 256);
  k_transpose<<<dim3(8,32),  dim3(32,32), 0, stream>>>(aWhhB, WT + 786432, 1024, 256);
  k_transpose<<<dim3(51,16), dim3(32,32), 0, stream>>>(fc1W, W1T, 512, 1626);

  // 2. ctx input projections (x @ Wih^T + b)
  k_gemm<0><<<dim3(16,16,1),256,0,stream>>>(left, 300,0,0,  cWihF,300,0,0,  PREf,           1024,0,0,
      nullptr,0,0, nullptr,0,0, nullptr,0,0, cbF, 1024,1024,300, 1);
  k_gemm<0><<<dim3(16,16,1),256,0,stream>>>(right,300,0,0,  cWihF,300,0,0,  PREf+1048576,   1024,0,0,
      nullptr,0,0, nullptr,0,0, nullptr,0,0, cbF, 1024,1024,300, 1);
  k_gemm<0><<<dim3(16,16,1),256,0,stream>>>(left, 300,0,0,  cWihB,300,0,0,  PREb,           1024,0,0,
      nullptr,0,0, nullptr,0,0, nullptr,0,0, cbB, 1024,1024,300, 1);
  k_gemm<0><<<dim3(16,16,1),256,0,stream>>>(right,300,0,0,  cWihB,300,0,0,  PREb+1048576,   1024,0,0,
      nullptr,0,0, nullptr,0,0, nullptr,0,0, cbB, 1024,1024,300, 1);

  // 3. ctx scan (8 WGs/dir, weights in VGPRs, per-half-wave exchange)
  hipMemsetAsync(FLG, 0, 512*sizeof(int), stream);
  k_scan5<<<64,256,0,stream>>>(PREf, PREb, WT, WT+262144, HXB, FLG, HS, nullptr);

  // 4. row norms
  k_rownorm<<<1024,256,0,stream>>>(HS, NORM);

  // 5. att (cosine matrix), z = d*4+b
  k_gemm<1><<<dim3(4,4,8),256,0,stream>>>(HS,512,256,131072,  HS+524288,512,256,131072,
      ATT,256,262144,65536,  nullptr,0,0,  NORM,256,512,  NORM+2048,256,512,
      nullptr, 256,256,256, 4);

  // 6-7. att reductions
  k_rowred<<<512,256,0,stream>>>(ATT, RS, RMAX, 256);
  k_colred<<<dim3(1,1,8),256,0,stream>>>(ATT, 65536, 256, 256, CS, CMAX);

  // 8. attentive means and maxes
  k_gemm<2><<<dim3(4,4,8),256,0,stream>>>(ATT,256,262144,65536,  HS+524288,512,256,131072,
      MEANH,256,262144,65536,  nullptr,0,0,  RS,1024,256,  nullptr,0,0, nullptr, 256,256,256, 4);
  k_gemm<4><<<dim3(4,4,8),256,0,stream>>>(ATT,256,262144,65536,  HS,512,256,131072,
      MEANP,256,262144,65536,  nullptr,0,0,  CS,1024,256,  nullptr,0,0, nullptr, 256,256,256, 4);
  k_gemm<3><<<dim3(4,4,8),256,0,stream>>>(ATT,256,262144,65536,  HS+524288,512,256,131072,
      XH,256,262144,65536,  nullptr,0,0,  nullptr,0,0,  nullptr,0,0, nullptr, 256,256,256, 4);
  k_gemm<5><<<dim3(4,4,8),256,0,stream>>>(ATT,256,262144,65536,  HS,512,256,131072,
      XP,256,262144,65536,  nullptr,0,0,  nullptr,0,0,  nullptr,0,0, nullptr, 256,256,256, 4);

  // 9. weighted norms
  k_wnorm<<<10240,256,0,stream>>>(HS, w3, w4, WN1, WN2);

  // 10-13. pairwise mm (fw then bw, buffer reused), z = b*10+l
  k_gemm<1><<<dim3(4,4,40),256,0,stream>>>(HS,512,131072,0,  HS+524288,512,131072,0,
      MM,256,655360,65536,  w3,0,256,  WN1,2560,256,  WN2,2560,256,
      nullptr, 256,256,256, 10);
  k_rowred<<<2560,256,0,stream>>>(MM, nullptr, MMR, 256);
  k_colred<<<dim3(1,1,40),256,0,stream>>>(MM, 65536, 256, 256, nullptr, MMC);
  k_gemm<1><<<dim3(4,4,40),256,0,stream>>>(HS+256,512,131072,0,  HS+524288+256,512,131072,0,
      MM,256,655360,65536,  w4,0,256,  WN1+10240,2560,256,  WN2+10240,2560,256,
      nullptr, 256,256,256, 10);
  k_rowred<<<2560,256,0,stream>>>(MM, nullptr, MMR+10240, 256);
  k_colred<<<dim3(1,1,40),256,0,stream>>>(MM, 65536, 256, 256, nullptr, MMC+10240);

  // 14. assemble mv (2048 rows x 62)
  k_mv<<<2048,256,0,stream>>>(HS, MEANH, MEANP, XH, XP, RS, RMAX, CS, CMAX,
                              MMR, MMC, w5, w6, w7, w8, MV);

  // 15. agg projections
  k_gemm<0><<<dim3(16,32,1),256,0,stream>>>(MV,62,0,0,  aWihF,62,0,0,  PREf,1024,0,0,
      nullptr,0,0, nullptr,0,0, nullptr,0,0, abF, 2048,1024,62, 1);
  k_gemm<0><<<dim3(16,32,1),256,0,stream>>>(MV,62,0,0,  aWihB,62,0,0,  PREb,1024,0,0,
      nullptr,0,0, nullptr,0,0, nullptr,0,0, abB, 2048,1024,62, 1);

  // 16. agg scan (keep only final h)
  hipMemsetAsync(FLG, 0, 512*sizeof(int), stream);
  k_scan5<<<64,256,0,stream>>>(PREf, PREb, WT+524288, WT+786432, HXB, FLG, nullptr, HT);

  // 17-19. head
  k_means<<<8,320,0,stream>>>(left, right, XM);
  k_fc1<<<4,512,0,stream>>>(HT, XM, W1T, fc1b, X2);
  k_fc2<<<4,64,0,stream>>>(X2, fc2W, fc2b, out);
}